// Round 17
// baseline (148.215 us; speedup 1.0000x reference)
//
#include <hip/hip_runtime.h>

#define CH    64
#define HWHW  1024      // 32*32
#define CHW   65536     // 64*1024
#define NPIX  32768.0f  // N*H*W per channel

#define QS16   4096.0f            // 2^12 quant scale
#define QB16   32768.5f           // 8*4096 bias + 0.5 round
#define Q0P    0x80008000u        // quant16(0) packed in both halves
#define QINV16 2.44140625e-4f     // 2^-12

#define PLSTRIDE 520              // dwords per plane image (10*52)
#define ROWSTR   52               // dwords per row (16B-aligned rows)
#define NPLANES  4096             // 32 n * 4 rg * 32 pairs

__device__ __forceinline__ unsigned q16(float x) {
  unsigned u = (unsigned)fmaf(x, QS16, QB16);   // negative saturates to 0
  return u > 65535u ? 65535u : u;
}
__device__ __forceinline__ unsigned q16pk(float lo, float hi) {
  return q16(lo) | (q16(hi) << 16);
}

// acc += |x.lo16-w.lo16| + |x.hi16-w.hi16| : TWO terms per VALU instruction
__device__ __forceinline__ unsigned sad16(unsigned x, unsigned w, unsigned a) {
  unsigned d;
  asm("v_sad_u16 %0, %1, %2, %3" : "=v"(d) : "v"(x), "v"(w), "v"(a));
  return d;
}

// ---------------- prep: quantize+pack weights (2 ci planes / u32) ----------
// dst u32 idx = cog*1152 + wv*288 + cp*36 + kh*12 + kw*4 + colo
__global__ __launch_bounds__(256) void prep_kernel(
    const float* __restrict__ w1, const float* __restrict__ w2,
    unsigned* __restrict__ wt1, unsigned* __restrict__ wt2,
    float* __restrict__ stats) {
  int j = blockIdx.x * 256 + threadIdx.x;
  if (j < 256) stats[j] = 0.0f;
  if (j < 18432) {
    int colo = j & 3;
    int t = j >> 2;
    int kw = t % 3; t /= 3;
    int kh = t % 3; t /= 3;
    int cp = t & 7; t >>= 3;
    int wv = t & 3; int cog = t >> 2;
    int co  = cog * 4 + colo;
    int cil = wv * 16 + cp * 2;
    int slo = co * 576 + cil * 9 + kh * 3 + kw;   // [co][ci][kh][kw]
    wt1[j] = q16pk(w1[slo], w1[slo + 9]);
    wt2[j] = q16pk(w2[slo], w2[slo + 9]);
  }
}

// ---------------- qx: pre-quantize x into plane images ------------
// xq[pl][520], pl = (n*4+rg)*32 + p (pair p = channels 2p,2p+1).
// Plane: row = j/52 (0..9), ci = j%52; data col c at ci=c+1 (ci 1..32),
// ci 0 = left halo, ci 33 = right halo, 34..51 pad; non-data = Q0P.
__global__ __launch_bounds__(256) void qx_kernel(
    const float* __restrict__ x, unsigned* __restrict__ xq) {
  int idx = blockIdx.x * 256 + threadIdx.x;
  if (idx >= NPLANES * PLSTRIDE) return;
  int pl = idx / PLSTRIDE;
  int j  = idx - pl * PLSTRIDE;
  int p  = pl & 31;
  int rg = (pl >> 5) & 3;
  int n  = pl >> 7;
  int row = j / ROWSTR;
  int ci  = j - row * ROWSTR;
  int col = ci - 1;
  int hr  = rg * 8 - 1 + row;
  unsigned v = Q0P;
  if (ci >= 1 && ci <= 32 && hr >= 0 && hr < 32) {
    const float* px = x + n * CHW + (2 * p) * HWHW + hr * 32 + col;
    v = q16pk(px[0], px[HWHW]);
  }
  xq[idx] = v;
}

// ---------------- bnq: BN + ReLU + quantize + pack (layer-2 input) ----------
__global__ __launch_bounds__(256) void bnq_kernel(
    const float* __restrict__ A, const float* __restrict__ stats,
    const float* __restrict__ g, const float* __restrict__ b,
    unsigned* __restrict__ xq) {
  int idx = blockIdx.x * 256 + threadIdx.x;
  if (idx >= NPLANES * PLSTRIDE) return;
  int pl = idx / PLSTRIDE;
  int j  = idx - pl * PLSTRIDE;
  int p  = pl & 31;
  int rg = (pl >> 5) & 3;
  int n  = pl >> 7;
  int row = j / ROWSTR;
  int ci  = j - row * ROWSTR;
  int col = ci - 1;
  int hr  = rg * 8 - 1 + row;
  unsigned v = Q0P;
  if (ci >= 1 && ci <= 32 && hr >= 0 && hr < 32) {
    int ch0 = 2 * p, ch1 = 2 * p + 1;
    float mu0 = stats[ch0] * (1.0f / NPIX);
    float va0 = fmaf(-mu0, mu0, stats[64 + ch0] * (1.0f / NPIX));
    float rs0 = rsqrtf(va0 + 1e-5f);
    float ga0 = g[ch0] * rs0;
    float be0 = fmaf(-mu0, ga0, b[ch0]);
    float mu1 = stats[ch1] * (1.0f / NPIX);
    float va1 = fmaf(-mu1, mu1, stats[64 + ch1] * (1.0f / NPIX));
    float rs1 = rsqrtf(va1 + 1e-5f);
    float ga1 = g[ch1] * rs1;
    float be1 = fmaf(-mu1, ga1, b[ch1]);
    float v0 = fmaxf(fmaf(A[n * CHW + ch0 * HWHW + hr * 32 + col], ga0, be0), 0.0f);
    float v1 = fmaxf(fmaf(A[n * CHW + ch1 * HWHW + hr * 32 + col], ga1, be1), 0.0f);
    v = q16pk(v0, v1);
  }
  xq[idx] = v;
}

// ---------------- adder2d + fused per-channel stats ----------------
// grid (16 cog, 4 rg, 32 n) = 2048 blocks, block 256 (4 waves).
// Wave wv sums ci pairs p = wv*8..wv*8+7. NO LDS in the main loop.
// BOTH x and w ping-pong one full plane ahead; sched_barrier(0) after each
// issue cluster pins the prefetch in place (R14's VGPR=36 proved the
// scheduler was sinking the loads to just before their use, exposing full
// memory latency per plane). launch_bounds(256,3): pipeline liveness
// ~130-140 VGPR needs the 170 cap; (256,4)'s 128 would spill.
__global__ __launch_bounds__(256, 3) void adder_kernel(
    const unsigned* __restrict__ xq,  // [4096][520] packed plane images
    const unsigned* __restrict__ wt,  // [16][1152] packed weights
    float* __restrict__ out,          // [32][64][32][32] fp32
    float* __restrict__ stats) {      // [0..63]=sum, [64..127]=sumsq
  const int cog  = blockIdx.x;       // 0..15
  const int rg   = blockIdx.y;       // 0..3
  const int n    = blockIdx.z;       // 0..31
  const int tid  = threadIdx.x;
  const int lane = tid & 63;
  const int wv   = __builtin_amdgcn_readfirstlane(tid >> 6);  // wave 0..3
  const int co0  = cog * 4;
  const int r0   = lane >> 3;        // 0..7 row within group
  const int c0   = (lane & 7) * 4;   // 0,4,..,28

  __shared__ unsigned red[3][64][20];   // cross-wave reduce scratch (epilogue)

  // per-lane x window base: plane base + row*52 + c0 (16B aligned)
  const unsigned* gp = xq + (size_t)(((n * 4 + rg) * 32) + wv * 8) * PLSTRIDE
                          + r0 * ROWSTR + c0;
  const unsigned* wp0 = wt + cog * 1152 + wv * 288;   // + cp*36, wave-uniform

  unsigned acc[4][4];
#pragma unroll
  for (int co = 0; co < 4; ++co)
#pragma unroll
    for (int j = 0; j < 4; ++j) acc[co][j] = 0u;

  uint4 xA[3], xB[3];       // 3 rows x b128
  uint2 yA[3], yB[3];       //          + b64
  unsigned wA[36], wB[36];  // plane-level weight ping-pong

#define LOADX(X, Y, cp) do { \
    const unsigned* _p = gp + (cp) * PLSTRIDE; \
    X[0] = *(const uint4*)_p;               Y[0] = *(const uint2*)(_p + 4); \
    X[1] = *(const uint4*)(_p + ROWSTR);    Y[1] = *(const uint2*)(_p + ROWSTR + 4); \
    X[2] = *(const uint4*)(_p + 2*ROWSTR);  Y[2] = *(const uint2*)(_p + 2*ROWSTR + 4); \
  } while (0)

#define LOADW(D, cp) do { \
    const uint4* _w = (const uint4*)(wp0 + (cp) * 36); \
    _Pragma("unroll") \
    for (int _i = 0; _i < 9; ++_i) { \
      uint4 _q = _w[_i]; \
      D[4*_i] = _q.x; D[4*_i+1] = _q.y; D[4*_i+2] = _q.z; D[4*_i+3] = _q.w; \
    } \
  } while (0)

#define COMPUTE(X, Y, W) do { \
    _Pragma("unroll") \
    for (int kh = 0; kh < 3; ++kh) { \
      unsigned xv0 = X[kh].x, xv1 = X[kh].y, xv2 = X[kh].z; \
      unsigned xv3 = X[kh].w, xv4 = Y[kh].x, xv5 = Y[kh].y; \
      _Pragma("unroll") \
      for (int co = 0; co < 4; ++co) { \
        unsigned w0 = W[kh*12 + co], w1 = W[kh*12 + 4 + co], w2 = W[kh*12 + 8 + co]; \
        acc[co][0] = sad16(xv0, w0, acc[co][0]); \
        acc[co][1] = sad16(xv1, w0, acc[co][1]); \
        acc[co][2] = sad16(xv2, w0, acc[co][2]); \
        acc[co][3] = sad16(xv3, w0, acc[co][3]); \
        acc[co][0] = sad16(xv1, w1, acc[co][0]); \
        acc[co][1] = sad16(xv2, w1, acc[co][1]); \
        acc[co][2] = sad16(xv3, w1, acc[co][2]); \
        acc[co][3] = sad16(xv4, w1, acc[co][3]); \
        acc[co][0] = sad16(xv2, w2, acc[co][0]); \
        acc[co][1] = sad16(xv3, w2, acc[co][1]); \
        acc[co][2] = sad16(xv4, w2, acc[co][2]); \
        acc[co][3] = sad16(xv5, w2, acc[co][3]); \
      } \
    } \
  } while (0)

  // ---- prologue: plane 0 into A ----
  LOADX(xA, yA, 0);
  LOADW(wA, 0);

  // ---- main loop: 4 iters x 2 planes, x+w ping-pong, order PINNED ----
#pragma unroll 1
  for (int it = 0; it < 4; ++it) {
    const int p1 = 2 * it + 1;
    const int p2 = (p1 + 1) & 7;       // last iter: dummy reload of plane 0
    LOADX(xB, yB, p1);
    LOADW(wB, p1);
    __builtin_amdgcn_sched_barrier(0);  // loads above CANNOT sink below
    COMPUTE(xA, yA, wA);                // plane 2it
    LOADX(xA, yA, p2);
    LOADW(wA, p2);
    __builtin_amdgcn_sched_barrier(0);
    COMPUTE(xB, yB, wB);                // plane p1
  }

  // ---- cross-wave reduction ----
  __syncthreads();
  if (wv != 0) {
    unsigned* rp = &red[wv - 1][lane][0];
#pragma unroll
    for (int co = 0; co < 4; ++co) {
      uint4 q = {acc[co][0], acc[co][1], acc[co][2], acc[co][3]};
      *(uint4*)(rp + co * 4) = q;
    }
  }
  __syncthreads();

  // ---- wave0: sum partials, convert, negate, write out, fused stats ----
  if (wv == 0) {
#pragma unroll
    for (int s = 0; s < 3; ++s) {
      const unsigned* rp = &red[s][lane][0];
#pragma unroll
      for (int co = 0; co < 4; ++co) {
        uint4 q = *(const uint4*)(rp + co * 4);
        acc[co][0] += q.x; acc[co][1] += q.y; acc[co][2] += q.z; acc[co][3] += q.w;
      }
    }
    const int ob = n * CHW + (rg * 8 + r0) * 32 + c0;
#pragma unroll
    for (int co = 0; co < 4; ++co) {
      float t0 = -(float)acc[co][0] * QINV16;
      float t1 = -(float)acc[co][1] * QINV16;
      float t2 = -(float)acc[co][2] * QINV16;
      float t3 = -(float)acc[co][3] * QINV16;
      *(float4*)(out + ob + (co0 + co) * HWHW) = make_float4(t0, t1, t2, t3);
      float sm = t0 + t1 + t2 + t3;
      float sq = t0 * t0 + t1 * t1 + t2 * t2 + t3 * t3;
#pragma unroll
      for (int m = 1; m < 64; m <<= 1) {
        sm += __shfl_xor(sm, m);
        sq += __shfl_xor(sq, m);
      }
      if (lane == 0) {
        atomicAdd(stats + co0 + co, sm);
        atomicAdd(stats + 64 + co0 + co, sq);
      }
    }
  }
}

// ---------------- BN + residual + ReLU ----------------
__global__ __launch_bounds__(256) void final_kernel(
    const float* __restrict__ Cbuf, const float* __restrict__ stats,
    const float* __restrict__ g, const float* __restrict__ b,
    const float* __restrict__ xres, float* __restrict__ out) {
  int i = blockIdx.x * 256 + threadIdx.x;
  int c = (i >> 8) & 63;
  float mu  = stats[c] * (1.0f / NPIX);
  float var = fmaf(-mu, mu, stats[64 + c] * (1.0f / NPIX));
  float rs  = rsqrtf(var + 1e-5f);
  float ga  = g[c] * rs;
  float be  = fmaf(-mu, ga, b[c]);
  float4 v = ((const float4*)Cbuf)[i];
  float4 xr = ((const float4*)xres)[i];
  v.x = fmaxf(fmaf(v.x, ga, be) + xr.x, 0.0f);
  v.y = fmaxf(fmaf(v.y, ga, be) + xr.y, 0.0f);
  v.z = fmaxf(fmaf(v.z, ga, be) + xr.z, 0.0f);
  v.w = fmaxf(fmaf(v.w, ga, be) + xr.w, 0.0f);
  ((float4*)out)[i] = v;
}

extern "C" void kernel_launch(void* const* d_in, const int* in_sizes, int n_in,
                              void* d_out, int out_size, void* d_ws, size_t ws_size,
                              hipStream_t stream) {
  const float* x  = (const float*)d_in[0];
  const float* w1 = (const float*)d_in[1];
  const float* g1 = (const float*)d_in[2];
  const float* b1 = (const float*)d_in[3];
  const float* w2 = (const float*)d_in[4];
  const float* g2 = (const float*)d_in[5];
  const float* b2 = (const float*)d_in[6];
  float* outp = (float*)d_out;

  float* ws = (float*)d_ws;
  const size_t NEL = 2097152;          // 32*64*32*32
  float*    bufA  = ws;                              // adder out (both layers)
  unsigned* xq    = (unsigned*)(ws + NEL);           // 4096*520 u32 (8.5 MB)
  unsigned* wt1   = xq + (size_t)NPLANES * PLSTRIDE; // 18432 u32
  unsigned* wt2   = wt1 + 18432;                     // 18432 u32
  float*    stats = (float*)(wt2 + 18432);           // 256 floats

  const int QGRID = (NPLANES * PLSTRIDE) / 256;      // 8320 blocks

  // 1. prep: pack weights, zero stats
  prep_kernel<<<72, 256, 0, stream>>>(w1, w2, wt1, wt2, stats);
  // 2. pre-quantize x into plane images
  qx_kernel<<<QGRID, 256, 0, stream>>>(x, xq);

  dim3 agrid(16, 4, 32);
  // 3. adder1: xq -> bufA, stats1
  adder_kernel<<<agrid, 256, 0, stream>>>(xq, wt1, bufA, stats);
  // 4. bn1 + relu + quantize + pack: bufA -> xq (reused)
  bnq_kernel<<<QGRID, 256, 0, stream>>>(bufA, stats, g1, b1, xq);
  // 5. adder2: xq -> bufA, stats2
  adder_kernel<<<agrid, 256, 0, stream>>>(xq, wt2, bufA, stats + 128);
  // 6. bn2 + residual + relu -> out
  final_kernel<<<2048, 256, 0, stream>>>(bufA, stats + 128, g2, b2, x, outp);
}

// Round 18
// 147.275 us; speedup vs baseline: 1.0064x; 1.0064x over previous
//
#include <hip/hip_runtime.h>

#define CH    64
#define HWHW  1024      // 32*32
#define CHW   65536     // 64*1024
#define NPIX  32768.0f  // N*H*W per channel

#define QS16   4096.0f            // 2^12 quant scale
#define QB16   32768.5f           // 8*4096 bias + 0.5 round
#define Q0P    0x80008000u        // quant16(0) packed in both halves
#define QINV16 2.44140625e-4f     // 2^-12

#define PLSTRIDE 520              // dwords per plane image (10*52)
#define ROWSTR   52               // dwords per row (16B-aligned rows)
#define NPLANES  4096             // 32 n * 4 rg * 32 pairs

__device__ __forceinline__ unsigned q16(float x) {
  unsigned u = (unsigned)fmaf(x, QS16, QB16);   // negative saturates to 0
  return u > 65535u ? 65535u : u;
}
__device__ __forceinline__ unsigned q16pk(float lo, float hi) {
  return q16(lo) | (q16(hi) << 16);
}

// acc += |x.lo16-w.lo16| + |x.hi16-w.hi16| : TWO terms per VALU instruction
__device__ __forceinline__ unsigned sad16(unsigned x, unsigned w, unsigned a) {
  unsigned d;
  asm("v_sad_u16 %0, %1, %2, %3" : "=v"(d) : "v"(x), "v"(w), "v"(a));
  return d;
}

// ---------------- prep: quantize+pack weights (2 ci planes / u32) ----------
// dst u32 idx = cog*1152 + wv*288 + cp*36 + kh*12 + kw*4 + colo
__global__ __launch_bounds__(256) void prep_kernel(
    const float* __restrict__ w1, const float* __restrict__ w2,
    unsigned* __restrict__ wt1, unsigned* __restrict__ wt2,
    float* __restrict__ stats) {
  int j = blockIdx.x * 256 + threadIdx.x;
  if (j < 256) stats[j] = 0.0f;
  if (j < 18432) {
    int colo = j & 3;
    int t = j >> 2;
    int kw = t % 3; t /= 3;
    int kh = t % 3; t /= 3;
    int cp = t & 7; t >>= 3;
    int wv = t & 3; int cog = t >> 2;
    int co  = cog * 4 + colo;
    int cil = wv * 16 + cp * 2;
    int slo = co * 576 + cil * 9 + kh * 3 + kw;   // [co][ci][kh][kw]
    wt1[j] = q16pk(w1[slo], w1[slo + 9]);
    wt2[j] = q16pk(w2[slo], w2[slo + 9]);
  }
}

// ---------------- qx: pre-quantize x into plane images ------------
// xq[pl][520], pl = (n*4+rg)*32 + p (pair p = channels 2p,2p+1).
// Plane: row = j/52 (0..9), ci = j%52; data col c at ci=c+1 (ci 1..32),
// ci 0 = left halo, ci 33 = right halo, 34..51 pad; non-data = Q0P.
__global__ __launch_bounds__(256) void qx_kernel(
    const float* __restrict__ x, unsigned* __restrict__ xq) {
  int idx = blockIdx.x * 256 + threadIdx.x;
  if (idx >= NPLANES * PLSTRIDE) return;
  int pl = idx / PLSTRIDE;
  int j  = idx - pl * PLSTRIDE;
  int p  = pl & 31;
  int rg = (pl >> 5) & 3;
  int n  = pl >> 7;
  int row = j / ROWSTR;
  int ci  = j - row * ROWSTR;
  int col = ci - 1;
  int hr  = rg * 8 - 1 + row;
  unsigned v = Q0P;
  if (ci >= 1 && ci <= 32 && hr >= 0 && hr < 32) {
    const float* px = x + n * CHW + (2 * p) * HWHW + hr * 32 + col;
    v = q16pk(px[0], px[HWHW]);
  }
  xq[idx] = v;
}

// ---------------- bnq: BN + ReLU + quantize + pack (layer-2 input) ----------
__global__ __launch_bounds__(256) void bnq_kernel(
    const float* __restrict__ A, const float* __restrict__ stats,
    const float* __restrict__ g, const float* __restrict__ b,
    unsigned* __restrict__ xq) {
  int idx = blockIdx.x * 256 + threadIdx.x;
  if (idx >= NPLANES * PLSTRIDE) return;
  int pl = idx / PLSTRIDE;
  int j  = idx - pl * PLSTRIDE;
  int p  = pl & 31;
  int rg = (pl >> 5) & 3;
  int n  = pl >> 7;
  int row = j / ROWSTR;
  int ci  = j - row * ROWSTR;
  int col = ci - 1;
  int hr  = rg * 8 - 1 + row;
  unsigned v = Q0P;
  if (ci >= 1 && ci <= 32 && hr >= 0 && hr < 32) {
    int ch0 = 2 * p, ch1 = 2 * p + 1;
    float mu0 = stats[ch0] * (1.0f / NPIX);
    float va0 = fmaf(-mu0, mu0, stats[64 + ch0] * (1.0f / NPIX));
    float rs0 = rsqrtf(va0 + 1e-5f);
    float ga0 = g[ch0] * rs0;
    float be0 = fmaf(-mu0, ga0, b[ch0]);
    float mu1 = stats[ch1] * (1.0f / NPIX);
    float va1 = fmaf(-mu1, mu1, stats[64 + ch1] * (1.0f / NPIX));
    float rs1 = rsqrtf(va1 + 1e-5f);
    float ga1 = g[ch1] * rs1;
    float be1 = fmaf(-mu1, ga1, b[ch1]);
    float v0 = fmaxf(fmaf(A[n * CHW + ch0 * HWHW + hr * 32 + col], ga0, be0), 0.0f);
    float v1 = fmaxf(fmaf(A[n * CHW + ch1 * HWHW + hr * 32 + col], ga1, be1), 0.0f);
    v = q16pk(v0, v1);
  }
  xq[idx] = v;
}

// ---------------- adder2d + fused per-channel stats ----------------
// grid (16 cog, 4 rg, 32 n) = 2048 blocks, block 256 (4 waves).
// Wave wv sums ci pairs p = wv*8..wv*8+7. NO LDS in the main loop.
// BOTH x and w ping-pong one full plane ahead; sched_barrier(0) after each
// issue cluster pins the prefetch in place (R14's VGPR=36 proved the
// scheduler was sinking the loads to just before their use, exposing full
// memory latency per plane). launch_bounds(256,3): pipeline liveness
// ~130-140 VGPR needs the 170 cap; (256,4)'s 128 would spill.
__global__ __launch_bounds__(256, 3) void adder_kernel(
    const unsigned* __restrict__ xq,  // [4096][520] packed plane images
    const unsigned* __restrict__ wt,  // [16][1152] packed weights
    float* __restrict__ out,          // [32][64][32][32] fp32
    float* __restrict__ stats) {      // [0..63]=sum, [64..127]=sumsq
  const int cog  = blockIdx.x;       // 0..15
  const int rg   = blockIdx.y;       // 0..3
  const int n    = blockIdx.z;       // 0..31
  const int tid  = threadIdx.x;
  const int lane = tid & 63;
  const int wv   = __builtin_amdgcn_readfirstlane(tid >> 6);  // wave 0..3
  const int co0  = cog * 4;
  const int r0   = lane >> 3;        // 0..7 row within group
  const int c0   = (lane & 7) * 4;   // 0,4,..,28

  __shared__ unsigned red[3][64][20];   // cross-wave reduce scratch (epilogue)

  // per-lane x window base: plane base + row*52 + c0 (16B aligned)
  const unsigned* gp = xq + (size_t)(((n * 4 + rg) * 32) + wv * 8) * PLSTRIDE
                          + r0 * ROWSTR + c0;
  const unsigned* wp0 = wt + cog * 1152 + wv * 288;   // + cp*36, wave-uniform

  unsigned acc[4][4];
#pragma unroll
  for (int co = 0; co < 4; ++co)
#pragma unroll
    for (int j = 0; j < 4; ++j) acc[co][j] = 0u;

  uint4 xA[3], xB[3];       // 3 rows x b128
  uint2 yA[3], yB[3];       //          + b64
  unsigned wA[36], wB[36];  // plane-level weight ping-pong

#define LOADX(X, Y, cp) do { \
    const unsigned* _p = gp + (cp) * PLSTRIDE; \
    X[0] = *(const uint4*)_p;               Y[0] = *(const uint2*)(_p + 4); \
    X[1] = *(const uint4*)(_p + ROWSTR);    Y[1] = *(const uint2*)(_p + ROWSTR + 4); \
    X[2] = *(const uint4*)(_p + 2*ROWSTR);  Y[2] = *(const uint2*)(_p + 2*ROWSTR + 4); \
  } while (0)

#define LOADW(D, cp) do { \
    const uint4* _w = (const uint4*)(wp0 + (cp) * 36); \
    _Pragma("unroll") \
    for (int _i = 0; _i < 9; ++_i) { \
      uint4 _q = _w[_i]; \
      D[4*_i] = _q.x; D[4*_i+1] = _q.y; D[4*_i+2] = _q.z; D[4*_i+3] = _q.w; \
    } \
  } while (0)

#define COMPUTE(X, Y, W) do { \
    _Pragma("unroll") \
    for (int kh = 0; kh < 3; ++kh) { \
      unsigned xv0 = X[kh].x, xv1 = X[kh].y, xv2 = X[kh].z; \
      unsigned xv3 = X[kh].w, xv4 = Y[kh].x, xv5 = Y[kh].y; \
      _Pragma("unroll") \
      for (int co = 0; co < 4; ++co) { \
        unsigned w0 = W[kh*12 + co], w1 = W[kh*12 + 4 + co], w2 = W[kh*12 + 8 + co]; \
        acc[co][0] = sad16(xv0, w0, acc[co][0]); \
        acc[co][1] = sad16(xv1, w0, acc[co][1]); \
        acc[co][2] = sad16(xv2, w0, acc[co][2]); \
        acc[co][3] = sad16(xv3, w0, acc[co][3]); \
        acc[co][0] = sad16(xv1, w1, acc[co][0]); \
        acc[co][1] = sad16(xv2, w1, acc[co][1]); \
        acc[co][2] = sad16(xv3, w1, acc[co][2]); \
        acc[co][3] = sad16(xv4, w1, acc[co][3]); \
        acc[co][0] = sad16(xv2, w2, acc[co][0]); \
        acc[co][1] = sad16(xv3, w2, acc[co][1]); \
        acc[co][2] = sad16(xv4, w2, acc[co][2]); \
        acc[co][3] = sad16(xv5, w2, acc[co][3]); \
      } \
    } \
  } while (0)

  // ---- prologue: plane 0 into A ----
  LOADX(xA, yA, 0);
  LOADW(wA, 0);

  // ---- main loop: 4 iters x 2 planes, x+w ping-pong, order PINNED ----
#pragma unroll 1
  for (int it = 0; it < 4; ++it) {
    const int p1 = 2 * it + 1;
    const int p2 = (p1 + 1) & 7;       // last iter: dummy reload of plane 0
    LOADX(xB, yB, p1);
    LOADW(wB, p1);
    __builtin_amdgcn_sched_barrier(0);  // loads above CANNOT sink below
    COMPUTE(xA, yA, wA);                // plane 2it
    LOADX(xA, yA, p2);
    LOADW(wA, p2);
    __builtin_amdgcn_sched_barrier(0);
    COMPUTE(xB, yB, wB);                // plane p1
  }

  // ---- cross-wave reduction ----
  __syncthreads();
  if (wv != 0) {
    unsigned* rp = &red[wv - 1][lane][0];
#pragma unroll
    for (int co = 0; co < 4; ++co) {
      uint4 q = {acc[co][0], acc[co][1], acc[co][2], acc[co][3]};
      *(uint4*)(rp + co * 4) = q;
    }
  }
  __syncthreads();

  // ---- wave0: sum partials, convert, negate, write out, fused stats ----
  if (wv == 0) {
#pragma unroll
    for (int s = 0; s < 3; ++s) {
      const unsigned* rp = &red[s][lane][0];
#pragma unroll
      for (int co = 0; co < 4; ++co) {
        uint4 q = *(const uint4*)(rp + co * 4);
        acc[co][0] += q.x; acc[co][1] += q.y; acc[co][2] += q.z; acc[co][3] += q.w;
      }
    }
    const int ob = n * CHW + (rg * 8 + r0) * 32 + c0;
#pragma unroll
    for (int co = 0; co < 4; ++co) {
      float t0 = -(float)acc[co][0] * QINV16;
      float t1 = -(float)acc[co][1] * QINV16;
      float t2 = -(float)acc[co][2] * QINV16;
      float t3 = -(float)acc[co][3] * QINV16;
      *(float4*)(out + ob + (co0 + co) * HWHW) = make_float4(t0, t1, t2, t3);
      float sm = t0 + t1 + t2 + t3;
      float sq = t0 * t0 + t1 * t1 + t2 * t2 + t3 * t3;
#pragma unroll
      for (int m = 1; m < 64; m <<= 1) {
        sm += __shfl_xor(sm, m);
        sq += __shfl_xor(sq, m);
      }
      if (lane == 0) {
        atomicAdd(stats + co0 + co, sm);
        atomicAdd(stats + 64 + co0 + co, sq);
      }
    }
  }
}

// ---------------- BN + residual + ReLU ----------------
__global__ __launch_bounds__(256) void final_kernel(
    const float* __restrict__ Cbuf, const float* __restrict__ stats,
    const float* __restrict__ g, const float* __restrict__ b,
    const float* __restrict__ xres, float* __restrict__ out) {
  int i = blockIdx.x * 256 + threadIdx.x;
  int c = (i >> 8) & 63;
  float mu  = stats[c] * (1.0f / NPIX);
  float var = fmaf(-mu, mu, stats[64 + c] * (1.0f / NPIX));
  float rs  = rsqrtf(var + 1e-5f);
  float ga  = g[c] * rs;
  float be  = fmaf(-mu, ga, b[c]);
  float4 v = ((const float4*)Cbuf)[i];
  float4 xr = ((const float4*)xres)[i];
  v.x = fmaxf(fmaf(v.x, ga, be) + xr.x, 0.0f);
  v.y = fmaxf(fmaf(v.y, ga, be) + xr.y, 0.0f);
  v.z = fmaxf(fmaf(v.z, ga, be) + xr.z, 0.0f);
  v.w = fmaxf(fmaf(v.w, ga, be) + xr.w, 0.0f);
  ((float4*)out)[i] = v;
}

extern "C" void kernel_launch(void* const* d_in, const int* in_sizes, int n_in,
                              void* d_out, int out_size, void* d_ws, size_t ws_size,
                              hipStream_t stream) {
  const float* x  = (const float*)d_in[0];
  const float* w1 = (const float*)d_in[1];
  const float* g1 = (const float*)d_in[2];
  const float* b1 = (const float*)d_in[3];
  const float* w2 = (const float*)d_in[4];
  const float* g2 = (const float*)d_in[5];
  const float* b2 = (const float*)d_in[6];
  float* outp = (float*)d_out;

  float* ws = (float*)d_ws;
  const size_t NEL = 2097152;          // 32*64*32*32
  float*    bufA  = ws;                              // adder out (both layers)
  unsigned* xq    = (unsigned*)(ws + NEL);           // 4096*520 u32 (8.5 MB)
  unsigned* wt1   = xq + (size_t)NPLANES * PLSTRIDE; // 18432 u32
  unsigned* wt2   = wt1 + 18432;                     // 18432 u32
  float*    stats = (float*)(wt2 + 18432);           // 256 floats

  const int QGRID = (NPLANES * PLSTRIDE) / 256;      // 8320 blocks

  // 1. prep: pack weights, zero stats
  prep_kernel<<<72, 256, 0, stream>>>(w1, w2, wt1, wt2, stats);
  // 2. pre-quantize x into plane images
  qx_kernel<<<QGRID, 256, 0, stream>>>(x, xq);

  dim3 agrid(16, 4, 32);
  // 3. adder1: xq -> bufA, stats1
  adder_kernel<<<agrid, 256, 0, stream>>>(xq, wt1, bufA, stats);
  // 4. bn1 + relu + quantize + pack: bufA -> xq (reused)
  bnq_kernel<<<QGRID, 256, 0, stream>>>(bufA, stats, g1, b1, xq);
  // 5. adder2: xq -> bufA, stats2
  adder_kernel<<<agrid, 256, 0, stream>>>(xq, wt2, bufA, stats + 128);
  // 6. bn2 + residual + relu -> out
  final_kernel<<<2048, 256, 0, stream>>>(bufA, stats + 128, g2, b2, x, outp);
}